// Round 6
// baseline (1454.411 us; speedup 1.0000x reference)
//
#include <hip/hip_runtime.h>

// DecoderLSTM (show-attend-tell) for MI355X — dataflow persistent version.
// B=64 T=32 F=512 L=196 E=512 H=512 A=512 V=10000, Tmax=31.
// Round-6: NO global barriers.  256 blocks = 4 independent groups of 64;
// group g owns batches [16g,16g+16) and steps to Tg = lengths[16g]-1.
// Phases sync via per-link producer->consumer FLAGS (sc1 monotone epochs):
//   A (local<24): de/fgate/hh = h @ [Wdec;Wfb;Whh].T   -> aflag[local]
//   B (all 64):   fused attention per (b, quarter)     -> zflag[local]
//   C (local<32): gates MFMA + LSTM pointwise -> h     -> hflag[dtC]
// Consumers poll only the flags they need (wave0), then asm memory barrier.
// WAR-safe by chain induction: A(t+1) > C(t) > B(t) > A(t) for each buffer.

typedef unsigned short ushort_t;
typedef __attribute__((ext_vector_type(8))) short short8;
typedef __attribute__((ext_vector_type(4))) float f32x4;

__device__ __forceinline__ float bf2f(ushort_t u) {
    unsigned x = ((unsigned)u) << 16;
    float f;
    __builtin_memcpy(&f, &x, 4);
    return f;
}
__device__ __forceinline__ ushort_t f2bf(float f) {
    unsigned x;
    __builtin_memcpy(&x, &f, 4);
    unsigned r = (x + 0x7fffu + ((x >> 16) & 1u)) >> 16;
    return (ushort_t)r;
}
__device__ __forceinline__ float sigmoidf_(float x) { return 1.f / (1.f + __expf(-x)); }
__device__ __forceinline__ float tanh_fast(float x) {
    float e = __expf(2.f * x);
    return 1.f - 2.f / (e + 1.f);
}
__device__ __forceinline__ float wred_sum(float v) {
    #pragma unroll
    for (int m = 32; m; m >>= 1) v += __shfl_xor(v, m, 64);
    return v;
}
__device__ __forceinline__ float wred_max(float v) {
    #pragma unroll
    for (int m = 32; m; m >>= 1) v = fmaxf(v, __shfl_xor(v, m, 64));
    return v;
}

// ---- agent-scope relaxed atomics: performed at LLC (sc1), no fences ----
__device__ __forceinline__ float aload_f(const float* p) {
    return __hip_atomic_load((float*)p, __ATOMIC_RELAXED, __HIP_MEMORY_SCOPE_AGENT);
}
__device__ __forceinline__ void astore_f(float* p, float v) {
    __hip_atomic_store(p, v, __ATOMIC_RELAXED, __HIP_MEMORY_SCOPE_AGENT);
}
__device__ __forceinline__ unsigned aload_u(const unsigned* p) {
    return __hip_atomic_load((unsigned*)p, __ATOMIC_RELAXED, __HIP_MEMORY_SCOPE_AGENT);
}
__device__ __forceinline__ void astore_u(unsigned* p, unsigned v) {
    __hip_atomic_store(p, v, __ATOMIC_RELAXED, __HIP_MEMORY_SCOPE_AGENT);
}
__device__ __forceinline__ int aload_i(const int* p) {
    return __hip_atomic_load((int*)p, __ATOMIC_RELAXED, __HIP_MEMORY_SCOPE_AGENT);
}
__device__ __forceinline__ void astore_i(int* p, int v) {
    __hip_atomic_store(p, v, __ATOMIC_RELAXED, __HIP_MEMORY_SCOPE_AGENT);
}

// exp2 scale: tanh(x) = 1 - 2/(2^(K*x)+1), K = 2*log2(e)
#define KEXP2 2.8853901817779268f

// ---- dtype detection (also zeroes the 512 flag words) ----
__global__ void detect_kernel(const unsigned* __restrict__ feat_raw, int* __restrict__ flag,
                              int* __restrict__ flags) {
    int lane = threadIdx.x;
    #pragma unroll
    for (int i = 0; i < 8; ++i) flags[lane + i * 64] = 0;
    unsigned u = feat_raw[lane];
    unsigned e = (u >> 7) & 0xffu;
    bool bf_like = (e >= 105 && e <= 133);
    unsigned long long m = __ballot(bf_like);
    if (lane == 0) *flag = (__popcll(m) >= 40) ? 0 : 1;  // 1 -> fp32 inputs
}

#define NCVT 19
struct CvtArgs {
    const void* src[NCVT];
    void* dst[NCVT];
    int n[NCVT];
};

__global__ __launch_bounds__(256) void convert_kernel(CvtArgs a, const int* __restrict__ flag) {
    const int ai = blockIdx.y;
    const int n = a.n[ai];
    const int base = (blockIdx.x * 256 + threadIdx.x) * 8;
    if (base >= n) return;
    ushort_t* dst = (ushort_t*)a.dst[ai];
    if (*flag) {
        const float* s = (const float*)a.src[ai];
        #pragma unroll
        for (int i = 0; i < 8; ++i) {
            int idx = base + i;
            if (idx < n) dst[idx] = f2bf(s[idx]);
        }
    } else {
        const ushort_t* s = (const ushort_t*)a.src[ai];
        #pragma unroll
        for (int i = 0; i < 8; ++i) {
            int idx = base + i;
            if (idx < n) dst[idx] = s[idx];
        }
    }
}

// ---- gather needed embedding rows -> bf16 [31*64, 512] ----
__global__ __launch_bounds__(256) void embrows_kernel(const void* __restrict__ Wemb,
                                                      const int* __restrict__ captions,
                                                      const int* __restrict__ flag,
                                                      ushort_t* __restrict__ emb_c) {
    const int tb = blockIdx.x;  // t*64 + b
    const int t = tb >> 6, b = tb & 63;
    const int cap = captions[b * 32 + t];
    const int e0 = threadIdx.x;
    if (*flag) {
        const float* s = (const float*)Wemb + cap * 512;
        emb_c[tb * 512 + e0] = f2bf(s[e0]);
        emb_c[tb * 512 + e0 + 256] = f2bf(s[e0 + 256]);
    } else {
        const ushort_t* s = (const ushort_t*)Wemb + cap * 512;
        emb_c[tb * 512 + e0] = s[e0];
        emb_c[tb * 512 + e0 + 256] = s[e0 + 256];
    }
}

// ---- w2[a] = -2*wf[a]; w2[512] = sum(wf)+b_full ----
__global__ void prepw2_kernel(const ushort_t* __restrict__ wf, const ushort_t* __restrict__ bfc,
                              float* __restrict__ w2) {
    int tid = threadIdx.x;  // 512
    float w = bf2f(wf[tid]);
    w2[tid] = -2.f * w;
    float s = wred_sum(w);
    __shared__ float r8[8];
    if ((tid & 63) == 0) r8[tid >> 6] = s;
    __syncthreads();
    if (tid == 0) {
        float tot = r8[0] + r8[1] + r8[2] + r8[3] + r8[4] + r8[5] + r8[6] + r8[7];
        w2[512] = tot + bf2f(bfc[0]);
    }
}

// ---- 64x64 MFMA tile, K=512, 256 threads (4 waves), bf16 in / fp32 acc ----
template <class AROW, class BROW, class EPI>
__device__ __forceinline__ void gemm_tile(AROW arow, BROW brow, EPI epi) {
    __shared__ __align__(16) ushort_t As[64][40];
    __shared__ __align__(16) ushort_t Bs[64][40];
    const int tid = threadIdx.x;
    const int row = tid >> 2, ks = (tid & 3) << 3;
    const int wave = tid >> 6, lane = tid & 63;
    const int quad = lane >> 4, l15 = lane & 15;
    f32x4 acc[4];
    #pragma unroll
    for (int s = 0; s < 4; ++s) acc[s] = (f32x4){0.f, 0.f, 0.f, 0.f};
    const ushort_t* ap = arow(row);
    const ushort_t* bp = brow(row);
    for (int k0 = 0; k0 < 512; k0 += 32) {
        short8 av = {0, 0, 0, 0, 0, 0, 0, 0};
        short8 bv = {0, 0, 0, 0, 0, 0, 0, 0};
        if (ap) av = *(const short8*)(ap + k0 + ks);
        if (bp) bv = *(const short8*)(bp + k0 + ks);
        __syncthreads();
        *(short8*)&As[row][ks] = av;
        *(short8*)&Bs[row][ks] = bv;
        __syncthreads();
        short8 af = *(const short8*)&As[(wave << 4) + l15][quad << 3];
        #pragma unroll
        for (int s = 0; s < 4; ++s) {
            short8 bfr = *(const short8*)&Bs[(s << 4) + l15][quad << 3];
            acc[s] = __builtin_amdgcn_mfma_f32_16x16x32_bf16(af, bfr, acc[s], 0, 0, 0);
        }
    }
    epi((wave << 4) + (quad << 2), l15, acc);
}

// ---- mean over L of features [B, F, L] -> bf16 [B, F] ----
__global__ __launch_bounds__(256) void mean_kernel(const ushort_t* __restrict__ features,
                                                   ushort_t* __restrict__ mean_bf) {
    const int b = blockIdx.x;
    const int wave = threadIdx.x >> 6, lane = threadIdx.x & 63;
    const ushort_t* fb = features + b * 512 * 196;
    for (int f = wave; f < 512; f += 4) {
        const ushort_t* r = fb + f * 196;
        float s = bf2f(r[lane]) + bf2f(r[lane + 64]) + bf2f(r[lane + 128]);
        if (lane < 4) s += bf2f(r[lane + 192]);
        s = wred_sum(s);
        if (lane == 0) mean_bf[b * 512 + f] = f2bf(s * (1.f / 196.f));
    }
}

// ---- h0 / c0 ----
__global__ __launch_bounds__(256) void init_kernel(
    const ushort_t* __restrict__ mean_bf, const ushort_t* __restrict__ Winh,
    const ushort_t* __restrict__ binh, const ushort_t* __restrict__ Winc,
    const ushort_t* __restrict__ binc, ushort_t* __restrict__ h_bf,
    float* __restrict__ cbuf) {
    const int n0 = blockIdx.x << 6;
    gemm_tile(
        [&](int r) { return mean_bf + r * 512; },
        [&](int r) {
            int n = n0 + r;
            return (n < 512) ? (Winh + n * 512) : (Winc + (n - 512) * 512);
        },
        [&](int mb, int l15, const f32x4* acc) {
            #pragma unroll
            for (int s = 0; s < 4; ++s) {
                int n = n0 + (s << 4) + l15;
                #pragma unroll
                for (int r = 0; r < 4; ++r) {
                    int b = mb + r;
                    if (n < 512)
                        h_bf[b * 512 + n] = f2bf(acc[s][r] + bf2f(binh[n]));
                    else
                        cbuf[b * 512 + (n - 512)] = acc[s][r] + bf2f(binc[n - 512]);
                }
            }
        });
}

// ---- en_att = feat_r @ W_enc.T + b_enc -> bf16 [12544, 512] ----
__global__ __launch_bounds__(256) void enatt_kernel(const ushort_t* __restrict__ feat,
                                                    const ushort_t* __restrict__ Wenc,
                                                    const ushort_t* __restrict__ benc,
                                                    ushort_t* __restrict__ en_att) {
    const int m0 = blockIdx.y << 6, n0 = blockIdx.x << 6;
    gemm_tile(
        [&](int r) { return feat + (m0 + r) * 512; },
        [&](int r) { return Wenc + (n0 + r) * 512; },
        [&](int mb, int l15, const f32x4* acc) {
            #pragma unroll
            for (int s = 0; s < 4; ++s) {
                int n = n0 + (s << 4) + l15;
                float bias = bf2f(benc[n]);
                #pragma unroll
                for (int r = 0; r < 4; ++r) {
                    int m = m0 + mb + r;
                    en_att[m * 512 + n] = f2bf(acc[s][r] + bias);
                }
            }
        });
}

// ---- ec[t,b,j] = emb_row @ W_ih[:, :512].T + b_ih + b_hh -> fp32 ----
__global__ __launch_bounds__(256) void ec_kernel(const ushort_t* __restrict__ emb_c,
                                                 const ushort_t* __restrict__ Wih,
                                                 const ushort_t* __restrict__ bih,
                                                 const ushort_t* __restrict__ bhh,
                                                 float* __restrict__ ec) {
    const int t = blockIdx.y, n0 = blockIdx.x << 6;
    gemm_tile(
        [&](int r) { return emb_c + (t * 64 + r) * 512; },
        [&](int r) { return Wih + (n0 + r) * 1024; },
        [&](int mb, int l15, const f32x4* acc) {
            #pragma unroll
            for (int s = 0; s < 4; ++s) {
                int j = n0 + (s << 4) + l15;
                float bias = bf2f(bih[j]) + bf2f(bhh[j]);
                #pragma unroll
                for (int r = 0; r < 4; ++r) {
                    int b = mb + r;
                    ec[(t * 64 + b) * 2048 + j] = acc[s][r] + bias;
                }
            }
        });
}

struct LoopArgs {
    const ushort_t* W3c;     // [3072][512] = [Wdec; Wfb; Whh]
    const ushort_t* bdec;
    const ushort_t* bfb;
    const ushort_t* en_att;  // [12544][512]
    const ushort_t* feat;    // [64][196][512]
    const ushort_t* Wih;     // [2048][1024]
    const float* w2;         // [513]: -2*wf, [512]=sum(wf)+b_full
    const float* ec;         // [1984][2048]
    const int* lengths;
    const int* flag;
    ushort_t* h_bf;
    ushort_t* z_bf;
    ushort_t* H_all;
    float* cbuf;
    float* deK;              // K*(h@Wdec.T + bdec)
    float* fgate;            // sigmoid(h@Wfb.T + bfb)
    float* hh;               // h@Whh.T
    void* out_base;
    int* flags;              // [4][128]: [0:32) hflag, [32:56) aflag, [64:128) zflag
};

// Persistent dataflow loop. 256 blocks x 512 threads, 1 block/CU.
__global__ __launch_bounds__(512, 2) void loop_kernel(LoopArgs A) {
    const int blk = blockIdx.x, tid = threadIdx.x;
    const int wave = tid >> 6, lane = tid & 63;
    const int quad = lane >> 4, l15 = lane & 15;
    const int g = blk >> 6, local = blk & 63;
    int* fbase = A.flags + g * 128;

    __shared__ __align__(16) ushort_t enS[49 * 512];    // en_att slice (bB, 49 l's)
    __shared__ __align__(16) ushort_t ftS[196 * 128];   // feat slice (bB, 128 f's)
    __shared__ __align__(16) ushort_t AsL[16][520];     // staged A-tile for MFMA
    __shared__ float smem[2048];                        // z partials | C gate acc
    __shared__ float fullS[200];                        // B: full / alpha
    __shared__ float red8[16];

    const int f32o = *A.flag;
    const int b0 = g << 4;                   // group's first batch
    const int Tg = A.lengths[b0] - 1;        // group's max dec_len (sorted desc)

    const bool roleA = local < 24;
    const int bB = b0 + (local >> 2);        // B role batch
    const int qB = local & 3;                // B role quarter
    const int lenB = A.lengths[bB];
    const bool roleC = local < 32;
    const int dtC = local;                   // C role dim-tile (if roleC)

    unsigned* h_u32 = (unsigned*)A.h_bf;
    unsigned* z_u32 = (unsigned*)A.z_bf;

    float w2r[8];
    {
        f32x4 w0 = *(const f32x4*)(A.w2 + lane * 8);
        f32x4 w1 = *(const f32x4*)(A.w2 + lane * 8 + 4);
        w2r[0] = w0[0]; w2r[1] = w0[1]; w2r[2] = w0[2]; w2r[3] = w0[3];
        w2r[4] = w1[0]; w2r[5] = w1[1]; w2r[6] = w1[2]; w2r[7] = w1[3];
    }
    const float fullc = A.w2[512];

    // one-time LDS pinning of this block's attention slices (B role)
    {
        const short8* src = (const short8*)(A.en_att + ((size_t)bB * 196 + qB * 49) * 512);
        short8* dst = (short8*)enS;
        for (int i = tid; i < 49 * 64; i += 512) dst[i] = src[i];
        const ushort_t* fsrc = A.feat + (size_t)bB * 100352 + qB * 128;
        short8* fdst = (short8*)ftS;
        for (int i = tid; i < 196 * 16; i += 512) {
            int l = i >> 4, c = i & 15;
            fdst[i] = *(const short8*)(fsrc + l * 512 + c * 8);
        }
    }
    // (first use of enS/ftS is after a __syncthreads below)

    for (int t = 0; t < Tg; ++t) {
        // ============ Phase A: de/fgate/hh = h @ [Wdec;Wfb;Whh].T ============
        if (roleA) {
            if (wave == 0 && t > 0) {        // wait h from all 32 C-blocks
                const int* fp = fbase + (lane & 31);
                for (;;) {
                    if (__all(aload_i(fp) >= t)) break;
                    __builtin_amdgcn_s_sleep(1);
                }
                asm volatile("" ::: "memory");
            }
            __syncthreads();
            for (int i = tid; i < 4096; i += 512) {   // stage h (16 rows, sc1)
                int r = i >> 8, c = i & 255;
                *(unsigned*)&AsL[r][c << 1] = aload_u(h_u32 + ((b0 + r) << 8) + c);
            }
            __syncthreads();
            const int nt = local * 8 + wave;          // 0..191
            const ushort_t* br = A.W3c + ((nt << 4) + l15) * 512 + (quad << 3);
            const ushort_t* arl = &AsL[l15][quad << 3];
            f32x4 acc = {0.f, 0.f, 0.f, 0.f};
            #pragma unroll
            for (int k0 = 0; k0 < 512; k0 += 32)
                acc = __builtin_amdgcn_mfma_f32_16x16x32_bf16(
                    *(const short8*)(arl + k0), *(const short8*)(br + k0), acc, 0, 0, 0);
            const int n = (nt << 4) + l15;
            #pragma unroll
            for (int r = 0; r < 4; ++r) {
                const int b = b0 + (quad << 2) + r;
                float v = acc[r];
                if (n < 512)
                    astore_f(A.deK + b * 512 + n, (v + bf2f(A.bdec[n])) * KEXP2);
                else if (n < 1024)
                    astore_f(A.fgate + b * 512 + (n - 512),
                             sigmoidf_(v + bf2f(A.bfb[n - 512])));
                else
                    astore_f(A.hh + b * 2048 + (n - 1024), v);
            }
            asm volatile("s_waitcnt vmcnt(0)" ::: "memory");
            __syncthreads();
            if (tid == 0) astore_i(fbase + 32 + local, t + 1);
        }

        // ===== Phase B (all 64): fused attention for (bB, qB).  Redundant
        // ===== full[0..195] (147 rows from L2), block-local softmax, z quarter.
        {
            if (wave == 0) {                 // wait deK+fgate: A-blocks 0..7
                const int* fp = fbase + 32 + (lane & 7);
                for (;;) {
                    if (__all(aload_i(fp) >= t + 1)) break;
                    __builtin_amdgcn_s_sleep(1);
                }
                asm volatile("" ::: "memory");
            }
            __syncthreads();
            const bool act = (lenB - 1) > t;
            const size_t aoff = 19840000ull + ((size_t)bB * 31 + t) * 196;
            if (act) {
                float dkr[8];
                const float* dk = A.deK + bB * 512 + lane * 8;
                #pragma unroll
                for (int j = 0; j < 8; ++j) dkr[j] = aload_f(dk + j);
                const ushort_t* enb = A.en_att + (size_t)bB * 100352;
                const int lp0 = qB * 49;
                for (int l = wave; l < 196; l += 8) {
                    const ushort_t* er = (l >= lp0 && l < lp0 + 49)
                                             ? (enS + (l - lp0) * 512)
                                             : (enb + l * 512);
                    short8 ev = *(const short8*)(er + lane * 8);
                    float acc = 0.f;
                    #pragma unroll
                    for (int j = 0; j < 8; ++j) {
                        float e2 = __builtin_amdgcn_exp2f(
                            fmaf(bf2f((ushort_t)ev[j]), KEXP2, dkr[j]));
                        acc = fmaf(w2r[j], __builtin_amdgcn_rcpf(e2 + 1.f), acc);
                    }
                    acc = wred_sum(acc);
                    if (lane == 0) fullS[l] = acc + fullc;
                }
                __syncthreads();
                float v = (tid < 196) ? fullS[tid] : -1e30f;
                float wm = wred_max(v);
                if (lane == 0) red8[wave] = wm;
                __syncthreads();
                float mx = fmaxf(fmaxf(fmaxf(red8[0], red8[1]), fmaxf(red8[2], red8[3])),
                                 fmaxf(fmaxf(red8[4], red8[5]), fmaxf(red8[6], red8[7])));
                float e = (tid < 196) ? __expf(v - mx) : 0.f;
                float sw = wred_sum(e);
                if (lane == 0) red8[8 + wave] = sw;
                __syncthreads();
                float tot = red8[8] + red8[9] + red8[10] + red8[11] +
                            red8[12] + red8[13] + red8[14] + red8[15];
                float inv = 1.f / tot;
                float a = e * inv;
                if (tid < 196) {
                    fullS[tid] = a;
                    if (qB == 0) {
                        if (f32o) ((float*)A.out_base)[aoff + tid] = a;
                        else ((ushort_t*)A.out_base)[aoff + tid] = f2bf(a);
                    }
                }
                __syncthreads();
                const int fl = tid & 127, gq = tid >> 7;
                float zacc = 0.f;
                #pragma unroll 4
                for (int l = gq; l < 196; l += 4)
                    zacc = fmaf(fullS[l], bf2f(ftS[l * 128 + fl]), zacc);
                smem[256 + (gq << 7) + fl] = zacc;
                __syncthreads();
                if (tid < 64) {
                    const int f0l = tid << 1;
                    float z0 = smem[256 + f0l] + smem[384 + f0l] +
                               smem[512 + f0l] + smem[640 + f0l];
                    float z1 = smem[257 + f0l] + smem[385 + f0l] +
                               smem[513 + f0l] + smem[641 + f0l];
                    const int f0 = (qB << 7) + f0l;
                    z0 *= aload_f(A.fgate + bB * 512 + f0);
                    z1 *= aload_f(A.fgate + bB * 512 + f0 + 1);
                    unsigned zp = (unsigned)f2bf(z0) | ((unsigned)f2bf(z1) << 16);
                    astore_u(z_u32 + bB * 256 + (f0 >> 1), zp);
                }
            } else {
                if (qB == 0 && tid < 196) {
                    if (f32o) ((float*)A.out_base)[aoff + tid] = 0.f;
                    else ((ushort_t*)A.out_base)[aoff + tid] = 0;
                }
            }
            asm volatile("s_waitcnt vmcnt(0)" ::: "memory");
            __syncthreads();
            if (tid == 0) astore_i(fbase + 64 + local, t + 1);
        }

        // ============ Phase C: gates = z @ Wih[:,512:].T + ec + hh; LSTM ============
        if (roleC) {
            if (wave == 0) {   // wait 64 zflags + 4 hh A-flags
                const int* zp = fbase + 64 + lane;
                for (;;) {
                    int v1 = aload_i(zp);
                    int v2 = (lane < 4)
                                 ? aload_i(fbase + 32 + 8 + lane * 4 + (dtC >> 3))
                                 : 0x7fffffff;
                    if (__all(v1 >= t + 1 && v2 >= t + 1)) break;
                    __builtin_amdgcn_s_sleep(1);
                }
                asm volatile("" ::: "memory");
            }
            __syncthreads();
            // prefetch hh (sc1) + ec (normal) before the MFMA
            float pe[8], ph[8];
            #pragma unroll
            for (int k = 0; k < 8; ++k) { pe[k] = 0.f; ph[k] = 0.f; }
            if (tid < 128) {
                const int bl = tid >> 3, p = tid & 7;
                const int bE = b0 + bl;
                const int dimE = (dtC << 4) + (p << 1);
                const int eb = (t * 64 + bE) * 2048, hb = bE * 2048;
                pe[0] = A.ec[eb + dimE];         pe[1] = A.ec[eb + dimE + 1];
                pe[2] = A.ec[eb + 512 + dimE];   pe[3] = A.ec[eb + 512 + dimE + 1];
                pe[4] = A.ec[eb + 1024 + dimE];  pe[5] = A.ec[eb + 1024 + dimE + 1];
                pe[6] = A.ec[eb + 1536 + dimE];  pe[7] = A.ec[eb + 1536 + dimE + 1];
                ph[0] = aload_f(A.hh + hb + dimE);
                ph[1] = aload_f(A.hh + hb + dimE + 1);
                ph[2] = aload_f(A.hh + hb + 512 + dimE);
                ph[3] = aload_f(A.hh + hb + 512 + dimE + 1);
                ph[4] = aload_f(A.hh + hb + 1024 + dimE);
                ph[5] = aload_f(A.hh + hb + 1024 + dimE + 1);
                ph[6] = aload_f(A.hh + hb + 1536 + dimE);
                ph[7] = aload_f(A.hh + hb + 1536 + dimE + 1);
            }
            for (int i = tid; i < 4096; i += 512) {  // stage z (16 rows, sc1)
                int r = i >> 8, c = i & 255;
                *(unsigned*)&AsL[r][c << 1] = aload_u(z_u32 + ((b0 + r) << 8) + c);
            }
            __syncthreads();
            const int gw = wave & 3, kh = wave >> 2;
            const int j = (gw << 9) + (dtC << 4) + l15;
            const ushort_t* br = A.Wih + j * 1024 + 512 + (kh << 8) + (quad << 3);
            const ushort_t* arl = &AsL[l15][(kh << 8) + (quad << 3)];
            f32x4 acc = {0.f, 0.f, 0.f, 0.f};
            #pragma unroll
            for (int k0 = 0; k0 < 256; k0 += 32)
                acc = __builtin_amdgcn_mfma_f32_16x16x32_bf16(
                    *(const short8*)(arl + k0), *(const short8*)(br + k0), acc, 0, 0, 0);
            #pragma unroll
            for (int r = 0; r < 4; ++r)
                smem[(wave << 8) + (((quad << 2) + r) << 4) + l15] = acc[r];
            __syncthreads();
            if (tid < 128) {
                const int bl = tid >> 3, p = tid & 7;
                const int b = b0 + bl;
                const int i0 = (bl << 4) + (p << 1);
                const int dim = (dtC << 4) + (p << 1);
                float ig0 = smem[i0] + smem[1024 + i0] + pe[0] + ph[0];
                float ig1 = smem[i0 + 1] + smem[1025 + i0] + pe[1] + ph[1];
                float fg0 = smem[256 + i0] + smem[1280 + i0] + pe[2] + ph[2];
                float fg1 = smem[257 + i0] + smem[1281 + i0] + pe[3] + ph[3];
                float gg0 = smem[512 + i0] + smem[1536 + i0] + pe[4] + ph[4];
                float gg1 = smem[513 + i0] + smem[1537 + i0] + pe[5] + ph[5];
                float og0 = smem[768 + i0] + smem[1792 + i0] + pe[6] + ph[6];
                float og1 = smem[769 + i0] + smem[1793 + i0] + pe[7] + ph[7];
                float co0 = A.cbuf[b * 512 + dim];      // block-private
                float co1 = A.cbuf[b * 512 + dim + 1];
                float cn0 = sigmoidf_(fg0) * co0 + sigmoidf_(ig0) * tanh_fast(gg0);
                float hn0 = sigmoidf_(og0) * tanh_fast(cn0);
                float cn1 = sigmoidf_(fg1) * co1 + sigmoidf_(ig1) * tanh_fast(gg1);
                float hn1 = sigmoidf_(og1) * tanh_fast(cn1);
                unsigned hp = (unsigned)f2bf(hn0) | ((unsigned)f2bf(hn1) << 16);
                *(unsigned*)&A.H_all[(t * 64 + b) * 512 + dim] = hp;  // post-kernel
                if (A.lengths[b] - 1 > t) {
                    A.cbuf[b * 512 + dim] = cn0;
                    A.cbuf[b * 512 + dim + 1] = cn1;
                    astore_u(h_u32 + b * 256 + (dim >> 1), hp);
                }
            }
            asm volatile("s_waitcnt vmcnt(0)" ::: "memory");
            __syncthreads();
            if (tid == 0) astore_i(fbase + dtC, t + 1);
        }
    }

    // post-loop: zero remaining alpha rows for this group's batches
    if (qB == 0) {
        for (int t = Tg; t < 31; ++t) {
            if (tid < 196) {
                const size_t aoff = 19840000ull + ((size_t)bB * 31 + t) * 196;
                if (f32o) ((float*)A.out_base)[aoff + tid] = 0.f;
                else ((ushort_t*)A.out_base)[aoff + tid] = 0;
            }
        }
    }
}

// ---- preds = H_all @ W_out.T + b_out, ragged-masked ----
// grid (31, 157): t varies fastest so 31 blocks sharing a Wout tile are
// adjacent in dispatch order -> tile stays in L2/LLC.
__global__ __launch_bounds__(256) void preds_kernel(
    const ushort_t* __restrict__ H_all, const ushort_t* __restrict__ Wout,
    const ushort_t* __restrict__ bout, const int* __restrict__ lengths,
    const int* __restrict__ flag, void* __restrict__ out_base) {
    const int t = blockIdx.x, n0 = blockIdx.y << 6;
    const int f32o = *flag;
    gemm_tile(
        [&](int r) { return H_all + (t * 64 + r) * 512; },
        [&](int r) -> const ushort_t* {
            int n = n0 + r;
            return (n < 10000) ? (Wout + n * 512) : (const ushort_t*)nullptr;
        },
        [&](int mb, int l15, const f32x4* acc) {
            #pragma unroll
            for (int s = 0; s < 4; ++s) {
                int n = n0 + (s << 4) + l15;
                if (n >= 10000) continue;
                float bias = bf2f(bout[n]);
                #pragma unroll
                for (int r = 0; r < 4; ++r) {
                    int b = mb + r;
                    bool act = lengths[b] > t + 1;
                    float val = act ? (acc[s][r] + bias) : 0.f;
                    size_t off = (size_t)b * 310000 + t * 10000 + n;
                    if (f32o) ((float*)out_base)[off] = val;
                    else ((ushort_t*)out_base)[off] = act ? f2bf(val) : (ushort_t)0;
                }
            }
        });
}

extern "C" void kernel_launch(void* const* d_in, const int* in_sizes, int n_in,
                              void* d_out, int out_size, void* d_ws, size_t ws_size,
                              hipStream_t stream) {
    const void* features = d_in[0];
    const int* captions = (const int*)d_in[1];
    const int* lengths = (const int*)d_in[2];
    const void* W_emb = d_in[3];

    char* ws = (char*)d_ws;
    size_t o = 0;
    auto alloc = [&](size_t bytes) {
        size_t r = o;
        o += (bytes + 255) & ~(size_t)255;
        return r;
    };
    // canonical bf16 copies
    ushort_t* feat_c  = (ushort_t*)(ws + alloc(6422528ull * 2));
    ushort_t* Wenc_c  = (ushort_t*)(ws + alloc(262144ull * 2));
    ushort_t* benc_c  = (ushort_t*)(ws + alloc(512 * 2));
    ushort_t* W3c     = (ushort_t*)(ws + alloc(3072ull * 512 * 2));  // [Wdec;Wfb;Whh]
    ushort_t* bdec_c  = (ushort_t*)(ws + alloc(512 * 2));
    ushort_t* wfull_c = (ushort_t*)(ws + alloc(512 * 2));
    ushort_t* bfull_c = (ushort_t*)(ws + alloc(2));
    ushort_t* bfb_c   = (ushort_t*)(ws + alloc(512 * 2));
    ushort_t* Wih_c   = (ushort_t*)(ws + alloc(2097152ull * 2));
    ushort_t* bih_c   = (ushort_t*)(ws + alloc(2048 * 2));
    ushort_t* bhh_c   = (ushort_t*)(ws + alloc(2048 * 2));
    ushort_t* Wout_c  = (ushort_t*)(ws + alloc(5120000ull * 2));
    ushort_t* bout_c  = (ushort_t*)(ws + alloc(10000 * 2));
    ushort_t* Winh_c  = (ushort_t*)(ws + alloc(262144ull * 2));
    ushort_t* binh_c  = (ushort_t*)(ws + alloc(512 * 2));
    ushort_t* Winc_c  = (ushort_t*)(ws + alloc(262144ull * 2));
    ushort_t* binc_c  = (ushort_t*)(ws + alloc(512 * 2));
    ushort_t* emb_c   = (ushort_t*)(ws + alloc(1984ull * 512 * 2));
    // intermediates
    ushort_t* en_att  = (ushort_t*)(ws + alloc(12544ull * 512 * 2));
    float*    ec      = (float*)(ws + alloc(1984ull * 2048 * 4));
    ushort_t* H_all   = (ushort_t*)(ws + alloc(1984ull * 512 * 2));
    ushort_t* h_bf    = (ushort_t*)(ws + alloc(64 * 512 * 2));
    float*    cbuf    = (float*)(ws + alloc(64 * 512 * 4));
    float*    deK     = (float*)(ws + alloc(64 * 512 * 4));
    float*    fgate   = (float*)(ws + alloc(64 * 512 * 4));
    float*    hh      = (float*)(ws + alloc(64ull * 2048 * 4));
    ushort_t* z_bf    = (ushort_t*)(ws + alloc(64 * 512 * 2));
    ushort_t* mean_bf = (ushort_t*)(ws + alloc(64 * 512 * 2));
    float*    w2buf   = (float*)(ws + alloc(513 * 4));
    int*      flag    = (int*)(ws + alloc(256));
    int*      flags   = (int*)(ws + alloc(512 * 4));

    detect_kernel<<<1, 64, 0, stream>>>((const unsigned*)features, flag, flags);

    CvtArgs ca;
    const void* srcs[NCVT] = {features, d_in[4], d_in[5], d_in[6], d_in[7], d_in[8],
                              d_in[9], d_in[10], d_in[11], d_in[12], d_in[13], d_in[14],
                              d_in[15], d_in[16], d_in[17], d_in[18], d_in[19], d_in[20],
                              d_in[21]};
    void* dsts[NCVT] = {feat_c, Wenc_c, benc_c, W3c /*Wdec*/, bdec_c, wfull_c, bfull_c,
                        W3c + 262144 /*Wfb*/, bfb_c, Wih_c, W3c + 524288 /*Whh*/,
                        bih_c, bhh_c, Wout_c, bout_c, Winh_c, binh_c, Winc_c, binc_c};
    int ns[NCVT] = {6422528, 262144, 512, 262144, 512, 512, 1, 262144, 512,
                    2097152, 1048576, 2048, 2048, 5120000, 10000, 262144, 512,
                    262144, 512};
    for (int i = 0; i < NCVT; ++i) {
        ca.src[i] = srcs[i];
        ca.dst[i] = dsts[i];
        ca.n[i] = ns[i];
    }
    convert_kernel<<<dim3(3136, NCVT), 256, 0, stream>>>(ca, flag);
    embrows_kernel<<<1984, 256, 0, stream>>>(W_emb, captions, flag, emb_c);
    prepw2_kernel<<<1, 512, 0, stream>>>(wfull_c, bfull_c, w2buf);

    mean_kernel<<<64, 256, 0, stream>>>(feat_c, mean_bf);
    init_kernel<<<16, 256, 0, stream>>>(mean_bf, Winh_c, binh_c, Winc_c, binc_c,
                                        h_bf, cbuf);
    enatt_kernel<<<dim3(8, 196), 256, 0, stream>>>(feat_c, Wenc_c, benc_c, en_att);
    ec_kernel<<<dim3(32, 31), 256, 0, stream>>>(emb_c, Wih_c, bih_c, bhh_c, ec);

    LoopArgs la;
    la.W3c = W3c; la.bdec = bdec_c; la.bfb = bfb_c;
    la.en_att = en_att; la.feat = feat_c; la.Wih = Wih_c;
    la.w2 = w2buf; la.ec = ec; la.lengths = lengths; la.flag = flag;
    la.h_bf = h_bf; la.z_bf = z_bf; la.H_all = H_all;
    la.cbuf = cbuf; la.deK = deK; la.fgate = fgate; la.hh = hh;
    la.out_base = d_out; la.flags = flags;
    loop_kernel<<<256, 512, 0, stream>>>(la);

    preds_kernel<<<dim3(31, 157), 256, 0, stream>>>(H_all, Wout_c, bout_c, lengths,
                                                    flag, d_out);
}

// Round 7
// 1176.587 us; speedup vs baseline: 1.2361x; 1.2361x over previous
//
#include <hip/hip_runtime.h>

// DecoderLSTM (show-attend-tell) for MI355X — dataflow persistent version.
// B=64 T=32 F=512 L=196 E=512 H=512 A=512 V=10000, Tmax=31.
// Round-7: R6 dataflow skeleton (4 independent 64-block groups, per-link
// producer->consumer sc1 flags, group-local early exit) with the B phase
// restored to the R5 split: B1 computes ONLY the 49 LDS-pinned rows
// (no 147-row L2/HBM re-read -> that was R6's 251MB FETCH regression),
// then a 4-block QUARTET mini-sync (bflags), then B2 gathers 196 fullv
// floats from LLC and does the (cheap, redundant) softmax + z quarter.
//   A (local<24): de/fgate/hh = h @ [Wdec;Wfb;Whh].T   -> aflag[local]
//   B (all 64):   B1 -> bflag -> quartet poll -> B2    -> zflag[local]
//   C (local<32): gates MFMA + LSTM pointwise -> h     -> hflag[dtC]
// WAR-safe by chain induction (fullv(t+1) after C(t) after all B2(t) reads).

typedef unsigned short ushort_t;
typedef __attribute__((ext_vector_type(8))) short short8;
typedef __attribute__((ext_vector_type(4))) float f32x4;

__device__ __forceinline__ float bf2f(ushort_t u) {
    unsigned x = ((unsigned)u) << 16;
    float f;
    __builtin_memcpy(&f, &x, 4);
    return f;
}
__device__ __forceinline__ ushort_t f2bf(float f) {
    unsigned x;
    __builtin_memcpy(&x, &f, 4);
    unsigned r = (x + 0x7fffu + ((x >> 16) & 1u)) >> 16;
    return (ushort_t)r;
}
__device__ __forceinline__ float sigmoidf_(float x) { return 1.f / (1.f + __expf(-x)); }
__device__ __forceinline__ float tanh_fast(float x) {
    float e = __expf(2.f * x);
    return 1.f - 2.f / (e + 1.f);
}
__device__ __forceinline__ float wred_sum(float v) {
    #pragma unroll
    for (int m = 32; m; m >>= 1) v += __shfl_xor(v, m, 64);
    return v;
}
__device__ __forceinline__ float wred_max(float v) {
    #pragma unroll
    for (int m = 32; m; m >>= 1) v = fmaxf(v, __shfl_xor(v, m, 64));
    return v;
}

// ---- agent-scope relaxed atomics: performed at LLC (sc1), no fences ----
__device__ __forceinline__ float aload_f(const float* p) {
    return __hip_atomic_load((float*)p, __ATOMIC_RELAXED, __HIP_MEMORY_SCOPE_AGENT);
}
__device__ __forceinline__ void astore_f(float* p, float v) {
    __hip_atomic_store(p, v, __ATOMIC_RELAXED, __HIP_MEMORY_SCOPE_AGENT);
}
__device__ __forceinline__ unsigned aload_u(const unsigned* p) {
    return __hip_atomic_load((unsigned*)p, __ATOMIC_RELAXED, __HIP_MEMORY_SCOPE_AGENT);
}
__device__ __forceinline__ void astore_u(unsigned* p, unsigned v) {
    __hip_atomic_store(p, v, __ATOMIC_RELAXED, __HIP_MEMORY_SCOPE_AGENT);
}
__device__ __forceinline__ int aload_i(const int* p) {
    return __hip_atomic_load((int*)p, __ATOMIC_RELAXED, __HIP_MEMORY_SCOPE_AGENT);
}
__device__ __forceinline__ void astore_i(int* p, int v) {
    __hip_atomic_store(p, v, __ATOMIC_RELAXED, __HIP_MEMORY_SCOPE_AGENT);
}

// exp2 scale: tanh(x) = 1 - 2/(2^(K*x)+1), K = 2*log2(e)
#define KEXP2 2.8853901817779268f

// ---- dtype detection (also zeroes the 1024 flag words) ----
__global__ void detect_kernel(const unsigned* __restrict__ feat_raw, int* __restrict__ flag,
                              int* __restrict__ flags) {
    int lane = threadIdx.x;
    #pragma unroll
    for (int i = 0; i < 16; ++i) flags[lane + i * 64] = 0;
    unsigned u = feat_raw[lane];
    unsigned e = (u >> 7) & 0xffu;
    bool bf_like = (e >= 105 && e <= 133);
    unsigned long long m = __ballot(bf_like);
    if (lane == 0) *flag = (__popcll(m) >= 40) ? 0 : 1;  // 1 -> fp32 inputs
}

#define NCVT 19
struct CvtArgs {
    const void* src[NCVT];
    void* dst[NCVT];
    int n[NCVT];
};

__global__ __launch_bounds__(256) void convert_kernel(CvtArgs a, const int* __restrict__ flag) {
    const int ai = blockIdx.y;
    const int n = a.n[ai];
    const int base = (blockIdx.x * 256 + threadIdx.x) * 8;
    if (base >= n) return;
    ushort_t* dst = (ushort_t*)a.dst[ai];
    if (*flag) {
        const float* s = (const float*)a.src[ai];
        #pragma unroll
        for (int i = 0; i < 8; ++i) {
            int idx = base + i;
            if (idx < n) dst[idx] = f2bf(s[idx]);
        }
    } else {
        const ushort_t* s = (const ushort_t*)a.src[ai];
        #pragma unroll
        for (int i = 0; i < 8; ++i) {
            int idx = base + i;
            if (idx < n) dst[idx] = s[idx];
        }
    }
}

// ---- gather needed embedding rows -> bf16 [31*64, 512] ----
__global__ __launch_bounds__(256) void embrows_kernel(const void* __restrict__ Wemb,
                                                      const int* __restrict__ captions,
                                                      const int* __restrict__ flag,
                                                      ushort_t* __restrict__ emb_c) {
    const int tb = blockIdx.x;  // t*64 + b
    const int t = tb >> 6, b = tb & 63;
    const int cap = captions[b * 32 + t];
    const int e0 = threadIdx.x;
    if (*flag) {
        const float* s = (const float*)Wemb + cap * 512;
        emb_c[tb * 512 + e0] = f2bf(s[e0]);
        emb_c[tb * 512 + e0 + 256] = f2bf(s[e0 + 256]);
    } else {
        const ushort_t* s = (const ushort_t*)Wemb + cap * 512;
        emb_c[tb * 512 + e0] = s[e0];
        emb_c[tb * 512 + e0 + 256] = s[e0 + 256];
    }
}

// ---- w2[a] = -2*wf[a]; w2[512] = sum(wf)+b_full ----
__global__ void prepw2_kernel(const ushort_t* __restrict__ wf, const ushort_t* __restrict__ bfc,
                              float* __restrict__ w2) {
    int tid = threadIdx.x;  // 512
    float w = bf2f(wf[tid]);
    w2[tid] = -2.f * w;
    float s = wred_sum(w);
    __shared__ float r8[8];
    if ((tid & 63) == 0) r8[tid >> 6] = s;
    __syncthreads();
    if (tid == 0) {
        float tot = r8[0] + r8[1] + r8[2] + r8[3] + r8[4] + r8[5] + r8[6] + r8[7];
        w2[512] = tot + bf2f(bfc[0]);
    }
}

// ---- 64x64 MFMA tile, K=512, 256 threads (4 waves), bf16 in / fp32 acc ----
template <class AROW, class BROW, class EPI>
__device__ __forceinline__ void gemm_tile(AROW arow, BROW brow, EPI epi) {
    __shared__ __align__(16) ushort_t As[64][40];
    __shared__ __align__(16) ushort_t Bs[64][40];
    const int tid = threadIdx.x;
    const int row = tid >> 2, ks = (tid & 3) << 3;
    const int wave = tid >> 6, lane = tid & 63;
    const int quad = lane >> 4, l15 = lane & 15;
    f32x4 acc[4];
    #pragma unroll
    for (int s = 0; s < 4; ++s) acc[s] = (f32x4){0.f, 0.f, 0.f, 0.f};
    const ushort_t* ap = arow(row);
    const ushort_t* bp = brow(row);
    for (int k0 = 0; k0 < 512; k0 += 32) {
        short8 av = {0, 0, 0, 0, 0, 0, 0, 0};
        short8 bv = {0, 0, 0, 0, 0, 0, 0, 0};
        if (ap) av = *(const short8*)(ap + k0 + ks);
        if (bp) bv = *(const short8*)(bp + k0 + ks);
        __syncthreads();
        *(short8*)&As[row][ks] = av;
        *(short8*)&Bs[row][ks] = bv;
        __syncthreads();
        short8 af = *(const short8*)&As[(wave << 4) + l15][quad << 3];
        #pragma unroll
        for (int s = 0; s < 4; ++s) {
            short8 bfr = *(const short8*)&Bs[(s << 4) + l15][quad << 3];
            acc[s] = __builtin_amdgcn_mfma_f32_16x16x32_bf16(af, bfr, acc[s], 0, 0, 0);
        }
    }
    epi((wave << 4) + (quad << 2), l15, acc);
}

// ---- mean over L of features [B, F, L] -> bf16 [B, F] ----
__global__ __launch_bounds__(256) void mean_kernel(const ushort_t* __restrict__ features,
                                                   ushort_t* __restrict__ mean_bf) {
    const int b = blockIdx.x;
    const int wave = threadIdx.x >> 6, lane = threadIdx.x & 63;
    const ushort_t* fb = features + b * 512 * 196;
    for (int f = wave; f < 512; f += 4) {
        const ushort_t* r = fb + f * 196;
        float s = bf2f(r[lane]) + bf2f(r[lane + 64]) + bf2f(r[lane + 128]);
        if (lane < 4) s += bf2f(r[lane + 192]);
        s = wred_sum(s);
        if (lane == 0) mean_bf[b * 512 + f] = f2bf(s * (1.f / 196.f));
    }
}

// ---- h0 / c0 ----
__global__ __launch_bounds__(256) void init_kernel(
    const ushort_t* __restrict__ mean_bf, const ushort_t* __restrict__ Winh,
    const ushort_t* __restrict__ binh, const ushort_t* __restrict__ Winc,
    const ushort_t* __restrict__ binc, ushort_t* __restrict__ h_bf,
    float* __restrict__ cbuf) {
    const int n0 = blockIdx.x << 6;
    gemm_tile(
        [&](int r) { return mean_bf + r * 512; },
        [&](int r) {
            int n = n0 + r;
            return (n < 512) ? (Winh + n * 512) : (Winc + (n - 512) * 512);
        },
        [&](int mb, int l15, const f32x4* acc) {
            #pragma unroll
            for (int s = 0; s < 4; ++s) {
                int n = n0 + (s << 4) + l15;
                #pragma unroll
                for (int r = 0; r < 4; ++r) {
                    int b = mb + r;
                    if (n < 512)
                        h_bf[b * 512 + n] = f2bf(acc[s][r] + bf2f(binh[n]));
                    else
                        cbuf[b * 512 + (n - 512)] = acc[s][r] + bf2f(binc[n - 512]);
                }
            }
        });
}

// ---- en_att = feat_r @ W_enc.T + b_enc -> bf16 [12544, 512] ----
__global__ __launch_bounds__(256) void enatt_kernel(const ushort_t* __restrict__ feat,
                                                    const ushort_t* __restrict__ Wenc,
                                                    const ushort_t* __restrict__ benc,
                                                    ushort_t* __restrict__ en_att) {
    const int m0 = blockIdx.y << 6, n0 = blockIdx.x << 6;
    gemm_tile(
        [&](int r) { return feat + (m0 + r) * 512; },
        [&](int r) { return Wenc + (n0 + r) * 512; },
        [&](int mb, int l15, const f32x4* acc) {
            #pragma unroll
            for (int s = 0; s < 4; ++s) {
                int n = n0 + (s << 4) + l15;
                float bias = bf2f(benc[n]);
                #pragma unroll
                for (int r = 0; r < 4; ++r) {
                    int m = m0 + mb + r;
                    en_att[m * 512 + n] = f2bf(acc[s][r] + bias);
                }
            }
        });
}

// ---- ec[t,b,j] = emb_row @ W_ih[:, :512].T + b_ih + b_hh -> fp32 ----
__global__ __launch_bounds__(256) void ec_kernel(const ushort_t* __restrict__ emb_c,
                                                 const ushort_t* __restrict__ Wih,
                                                 const ushort_t* __restrict__ bih,
                                                 const ushort_t* __restrict__ bhh,
                                                 float* __restrict__ ec) {
    const int t = blockIdx.y, n0 = blockIdx.x << 6;
    gemm_tile(
        [&](int r) { return emb_c + (t * 64 + r) * 512; },
        [&](int r) { return Wih + (n0 + r) * 1024; },
        [&](int mb, int l15, const f32x4* acc) {
            #pragma unroll
            for (int s = 0; s < 4; ++s) {
                int j = n0 + (s << 4) + l15;
                float bias = bf2f(bih[j]) + bf2f(bhh[j]);
                #pragma unroll
                for (int r = 0; r < 4; ++r) {
                    int b = mb + r;
                    ec[(t * 64 + b) * 2048 + j] = acc[s][r] + bias;
                }
            }
        });
}

struct LoopArgs {
    const ushort_t* W3c;     // [3072][512] = [Wdec; Wfb; Whh]
    const ushort_t* bdec;
    const ushort_t* bfb;
    const ushort_t* en_att;  // [12544][512]
    const ushort_t* feat;    // [64][196][512]
    const ushort_t* Wih;     // [2048][1024]
    const float* w2;         // [513]: -2*wf, [512]=sum(wf)+b_full
    const float* ec;         // [1984][2048]
    const int* lengths;
    const int* flag;
    ushort_t* h_bf;
    ushort_t* z_bf;
    ushort_t* H_all;
    float* cbuf;
    float* deK;              // K*(h@Wdec.T + bdec)
    float* fgate;            // sigmoid(h@Wfb.T + bfb)
    float* hh;               // h@Whh.T
    float* fullv;            // [64][196]
    void* out_base;
    int* flags;              // [4][256]: [0:32) h, [32:56) a, [64:128) z, [128:192) bq
};

// Persistent dataflow loop. 256 blocks x 512 threads, 1 block/CU.
__global__ __launch_bounds__(512, 2) void loop_kernel(LoopArgs A) {
    const int blk = blockIdx.x, tid = threadIdx.x;
    const int wave = tid >> 6, lane = tid & 63;
    const int quad = lane >> 4, l15 = lane & 15;
    const int g = blk >> 6, local = blk & 63;
    int* fbase = A.flags + g * 256;

    __shared__ __align__(16) ushort_t enS[49 * 512];    // en_att slice (bB, 49 l's)
    __shared__ __align__(16) ushort_t ftS[196 * 128];   // feat slice (bB, 128 f's)
    __shared__ __align__(16) ushort_t AsL[16][520];     // staged A-tile for MFMA
    __shared__ float smem[2048];                        // z partials | C gate acc
    __shared__ float fullS[200];                        // B: alpha
    __shared__ float red8[16];

    const int f32o = *A.flag;
    const int b0 = g << 4;                   // group's first batch
    const int Tg = A.lengths[b0] - 1;        // group's max dec_len (sorted desc)

    const bool roleA = local < 24;
    const int bB = b0 + (local >> 2);        // B role batch
    const int qB = local & 3;                // B role quarter
    const int lenB = A.lengths[bB];
    const bool roleC = local < 32;
    const int dtC = local;                   // C role dim-tile (if roleC)

    unsigned* h_u32 = (unsigned*)A.h_bf;
    unsigned* z_u32 = (unsigned*)A.z_bf;

    float w2r[8];
    {
        f32x4 w0 = *(const f32x4*)(A.w2 + lane * 8);
        f32x4 w1 = *(const f32x4*)(A.w2 + lane * 8 + 4);
        w2r[0] = w0[0]; w2r[1] = w0[1]; w2r[2] = w0[2]; w2r[3] = w0[3];
        w2r[4] = w1[0]; w2r[5] = w1[1]; w2r[6] = w1[2]; w2r[7] = w1[3];
    }
    const float fullc = A.w2[512];

    // one-time LDS pinning of this block's attention slices (B role)
    {
        const short8* src = (const short8*)(A.en_att + ((size_t)bB * 196 + qB * 49) * 512);
        short8* dst = (short8*)enS;
        for (int i = tid; i < 49 * 64; i += 512) dst[i] = src[i];
        const ushort_t* fsrc = A.feat + (size_t)bB * 100352 + qB * 128;
        short8* fdst = (short8*)ftS;
        for (int i = tid; i < 196 * 16; i += 512) {
            int l = i >> 4, c = i & 15;
            fdst[i] = *(const short8*)(fsrc + l * 512 + c * 8);
        }
    }
    // (first use of enS/ftS is after a __syncthreads below)

    for (int t = 0; t < Tg; ++t) {
        // ============ Phase A: de/fgate/hh = h @ [Wdec;Wfb;Whh].T ============
        if (roleA) {
            if (wave == 0 && t > 0) {        // wait h from all 32 C-blocks
                const int* fp = fbase + (lane & 31);
                for (;;) {
                    if (__all(aload_i(fp) >= t)) break;
                    __builtin_amdgcn_s_sleep(1);
                }
                asm volatile("" ::: "memory");
            }
            __syncthreads();
            for (int i = tid; i < 4096; i += 512) {   // stage h (16 rows, sc1)
                int r = i >> 8, c = i & 255;
                *(unsigned*)&AsL[r][c << 1] = aload_u(h_u32 + ((b0 + r) << 8) + c);
            }
            __syncthreads();
            const int nt = local * 8 + wave;          // 0..191
            const ushort_t* br = A.W3c + ((nt << 4) + l15) * 512 + (quad << 3);
            const ushort_t* arl = &AsL[l15][quad << 3];
            f32x4 acc = {0.f, 0.f, 0.f, 0.f};
            #pragma unroll
            for (int k0 = 0; k0 < 512; k0 += 32)
                acc = __builtin_amdgcn_mfma_f32_16x16x32_bf16(
                    *(const short8*)(arl + k0), *(const short8*)(br + k0), acc, 0, 0, 0);
            const int n = (nt << 4) + l15;
            #pragma unroll
            for (int r = 0; r < 4; ++r) {
                const int b = b0 + (quad << 2) + r;
                float v = acc[r];
                if (n < 512)
                    astore_f(A.deK + b * 512 + n, (v + bf2f(A.bdec[n])) * KEXP2);
                else if (n < 1024)
                    astore_f(A.fgate + b * 512 + (n - 512),
                             sigmoidf_(v + bf2f(A.bfb[n - 512])));
                else
                    astore_f(A.hh + b * 2048 + (n - 1024), v);
            }
            asm volatile("s_waitcnt vmcnt(0)" ::: "memory");
            __syncthreads();
            if (tid == 0) astore_i(fbase + 32 + local, t + 1);
        }

        // ===== Phase B: B1 (pinned quarter) -> bflag -> quartet -> B2 =====
        {
            if (wave == 0) {                 // wait deK (A 0..3) + fgate (A 4..7)
                const int* fp = fbase + 32 + (lane & 7);
                for (;;) {
                    if (__all(aload_i(fp) >= t + 1)) break;
                    __builtin_amdgcn_s_sleep(1);
                }
                asm volatile("" ::: "memory");
            }
            __syncthreads();
            const bool act = (lenB - 1) > t;
            const size_t aoff = 19840000ull + ((size_t)bB * 31 + t) * 196;
            if (act) {
                float dkr[8];
                const float* dk = A.deK + bB * 512 + lane * 8;
                #pragma unroll
                for (int j = 0; j < 8; ++j) dkr[j] = aload_f(dk + j);
                for (int i = wave; i < 49; i += 8) {
                    short8 ev = *(const short8*)(enS + i * 512 + lane * 8);
                    float acc = 0.f;
                    #pragma unroll
                    for (int j = 0; j < 8; ++j) {
                        float e2 = __builtin_amdgcn_exp2f(
                            fmaf(bf2f((ushort_t)ev[j]), KEXP2, dkr[j]));
                        acc = fmaf(w2r[j], __builtin_amdgcn_rcpf(e2 + 1.f), acc);
                    }
                    acc = wred_sum(acc);
                    if (lane == 0)
                        astore_f(A.fullv + bB * 196 + qB * 49 + i, acc + fullc);
                }
            }
            asm volatile("s_waitcnt vmcnt(0)" ::: "memory");
            __syncthreads();
            if (tid == 0) astore_i(fbase + 128 + local, t + 1);
            if (wave == 0) {                 // quartet mini-sync (4 bflags)
                const int* fp = fbase + 128 + (local & ~3) + (lane & 3);
                for (;;) {
                    if (__all(aload_i(fp) >= t + 1)) break;
                    __builtin_amdgcn_s_sleep(1);
                }
                asm volatile("" ::: "memory");
            }
            __syncthreads();
            if (act) {
                float v = (tid < 196) ? aload_f(A.fullv + bB * 196 + tid) : -1e30f;
                float wm = wred_max(v);
                if (lane == 0) red8[wave] = wm;
                __syncthreads();
                float mx = fmaxf(fmaxf(fmaxf(red8[0], red8[1]), fmaxf(red8[2], red8[3])),
                                 fmaxf(fmaxf(red8[4], red8[5]), fmaxf(red8[6], red8[7])));
                float e = (tid < 196) ? __expf(v - mx) : 0.f;
                float sw = wred_sum(e);
                if (lane == 0) red8[8 + wave] = sw;
                __syncthreads();
                float tot = red8[8] + red8[9] + red8[10] + red8[11] +
                            red8[12] + red8[13] + red8[14] + red8[15];
                float inv = 1.f / tot;
                float a = e * inv;
                if (tid < 196) {
                    fullS[tid] = a;
                    if (qB == 0) {
                        if (f32o) ((float*)A.out_base)[aoff + tid] = a;
                        else ((ushort_t*)A.out_base)[aoff + tid] = f2bf(a);
                    }
                }
                __syncthreads();
                const int fl = tid & 127, gq = tid >> 7;
                float zacc = 0.f;
                #pragma unroll 4
                for (int l = gq; l < 196; l += 4)
                    zacc = fmaf(fullS[l], bf2f(ftS[l * 128 + fl]), zacc);
                smem[256 + (gq << 7) + fl] = zacc;
                __syncthreads();
                if (tid < 64) {
                    const int f0l = tid << 1;
                    float z0 = smem[256 + f0l] + smem[384 + f0l] +
                               smem[512 + f0l] + smem[640 + f0l];
                    float z1 = smem[257 + f0l] + smem[385 + f0l] +
                               smem[513 + f0l] + smem[641 + f0l];
                    const int f0 = (qB << 7) + f0l;
                    z0 *= aload_f(A.fgate + bB * 512 + f0);
                    z1 *= aload_f(A.fgate + bB * 512 + f0 + 1);
                    unsigned zp = (unsigned)f2bf(z0) | ((unsigned)f2bf(z1) << 16);
                    astore_u(z_u32 + bB * 256 + (f0 >> 1), zp);
                }
            } else {
                if (qB == 0 && tid < 196) {
                    if (f32o) ((float*)A.out_base)[aoff + tid] = 0.f;
                    else ((ushort_t*)A.out_base)[aoff + tid] = 0;
                }
            }
            asm volatile("s_waitcnt vmcnt(0)" ::: "memory");
            __syncthreads();
            if (tid == 0) astore_i(fbase + 64 + local, t + 1);
        }

        // ============ Phase C: gates = z @ Wih[:,512:].T + ec + hh; LSTM ============
        if (roleC) {
            if (wave == 0) {   // wait 64 zflags + 4 hh A-flags
                const int* zp = fbase + 64 + lane;
                for (;;) {
                    int v1 = aload_i(zp);
                    int v2 = (lane < 4)
                                 ? aload_i(fbase + 32 + 8 + lane * 4 + (dtC >> 3))
                                 : 0x7fffffff;
                    if (__all(v1 >= t + 1 && v2 >= t + 1)) break;
                    __builtin_amdgcn_s_sleep(1);
                }
                asm volatile("" ::: "memory");
            }
            __syncthreads();
            // prefetch hh (sc1) + ec (normal) before the MFMA
            float pe[8], ph[8];
            #pragma unroll
            for (int k = 0; k < 8; ++k) { pe[k] = 0.f; ph[k] = 0.f; }
            if (tid < 128) {
                const int bl = tid >> 3, p = tid & 7;
                const int bE = b0 + bl;
                const int dimE = (dtC << 4) + (p << 1);
                const int eb = (t * 64 + bE) * 2048, hb = bE * 2048;
                pe[0] = A.ec[eb + dimE];         pe[1] = A.ec[eb + dimE + 1];
                pe[2] = A.ec[eb + 512 + dimE];   pe[3] = A.ec[eb + 512 + dimE + 1];
                pe[4] = A.ec[eb + 1024 + dimE];  pe[5] = A.ec[eb + 1024 + dimE + 1];
                pe[6] = A.ec[eb + 1536 + dimE];  pe[7] = A.ec[eb + 1536 + dimE + 1];
                ph[0] = aload_f(A.hh + hb + dimE);
                ph[1] = aload_f(A.hh + hb + dimE + 1);
                ph[2] = aload_f(A.hh + hb + 512 + dimE);
                ph[3] = aload_f(A.hh + hb + 512 + dimE + 1);
                ph[4] = aload_f(A.hh + hb + 1024 + dimE);
                ph[5] = aload_f(A.hh + hb + 1024 + dimE + 1);
                ph[6] = aload_f(A.hh + hb + 1536 + dimE);
                ph[7] = aload_f(A.hh + hb + 1536 + dimE + 1);
            }
            for (int i = tid; i < 4096; i += 512) {  // stage z (16 rows, sc1)
                int r = i >> 8, c = i & 255;
                *(unsigned*)&AsL[r][c << 1] = aload_u(z_u32 + ((b0 + r) << 8) + c);
            }
            __syncthreads();
            const int gw = wave & 3, kh = wave >> 2;
            const int j = (gw << 9) + (dtC << 4) + l15;
            const ushort_t* br = A.Wih + j * 1024 + 512 + (kh << 8) + (quad << 3);
            const ushort_t* arl = &AsL[l15][(kh << 8) + (quad << 3)];
            f32x4 acc = {0.f, 0.f, 0.f, 0.f};
            #pragma unroll
            for (int k0 = 0; k0 < 256; k0 += 32)
                acc = __builtin_amdgcn_mfma_f32_16x16x32_bf16(
                    *(const short8*)(arl + k0), *(const short8*)(br + k0), acc, 0, 0, 0);
            #pragma unroll
            for (int r = 0; r < 4; ++r)
                smem[(wave << 8) + (((quad << 2) + r) << 4) + l15] = acc[r];
            __syncthreads();
            if (tid < 128) {
                const int bl = tid >> 3, p = tid & 7;
                const int b = b0 + bl;
                const int i0 = (bl << 4) + (p << 1);
                const int dim = (dtC << 4) + (p << 1);
                float ig0 = smem[i0] + smem[1024 + i0] + pe[0] + ph[0];
                float ig1 = smem[i0 + 1] + smem[1025 + i0] + pe[1] + ph[1];
                float fg0 = smem[256 + i0] + smem[1280 + i0] + pe[2] + ph[2];
                float fg1 = smem[257 + i0] + smem[1281 + i0] + pe[3] + ph[3];
                float gg0 = smem[512 + i0] + smem[1536 + i0] + pe[4] + ph[4];
                float gg1 = smem[513 + i0] + smem[1537 + i0] + pe[5] + ph[5];
                float og0 = smem[768 + i0] + smem[1792 + i0] + pe[6] + ph[6];
                float og1 = smem[769 + i0] + smem[1793 + i0] + pe[7] + ph[7];
                float co0 = A.cbuf[b * 512 + dim];      // block-private
                float co1 = A.cbuf[b * 512 + dim + 1];
                float cn0 = sigmoidf_(fg0) * co0 + sigmoidf_(ig0) * tanh_fast(gg0);
                float hn0 = sigmoidf_(og0) * tanh_fast(cn0);
                float cn1 = sigmoidf_(fg1) * co1 + sigmoidf_(ig1) * tanh_fast(gg1);
                float hn1 = sigmoidf_(og1) * tanh_fast(cn1);
                unsigned hp = (unsigned)f2bf(hn0) | ((unsigned)f2bf(hn1) << 16);
                *(unsigned*)&A.H_all[(t * 64 + b) * 512 + dim] = hp;  // post-kernel
                if (A.lengths[b] - 1 > t) {
                    A.cbuf[b * 512 + dim] = cn0;
                    A.cbuf[b * 512 + dim + 1] = cn1;
                    astore_u(h_u32 + b * 256 + (dim >> 1), hp);
                }
            }
            asm volatile("s_waitcnt vmcnt(0)" ::: "memory");
            __syncthreads();
            if (tid == 0) astore_i(fbase + dtC, t + 1);
        }
    }

    // post-loop: zero remaining alpha rows for this group's batches
    if (qB == 0) {
        for (int t = Tg; t < 31; ++t) {
            if (tid < 196) {
                const size_t aoff = 19840000ull + ((size_t)bB * 31 + t) * 196;
                if (f32o) ((float*)A.out_base)[aoff + tid] = 0.f;
                else ((ushort_t*)A.out_base)[aoff + tid] = 0;
            }
        }
    }
}

// ---- preds = H_all @ W_out.T + b_out, ragged-masked ----
// grid (31, 157): t varies fastest so 31 blocks sharing a Wout tile are
// adjacent in dispatch order -> tile stays in L2/LLC.
__global__ __launch_bounds__(256) void preds_kernel(
    const ushort_t* __restrict__ H_all, const ushort_t* __restrict__ Wout,
    const ushort_t* __restrict__ bout, const int* __restrict__ lengths,
    const int* __restrict__ flag, void* __restrict__ out_base) {
    const int t = blockIdx.x, n0 = blockIdx.y << 6;
    const int f32o = *flag;
    gemm_tile(
        [&](int r) { return H_all + (t * 64 + r) * 512; },
        [&](int r) -> const ushort_t* {
            int n = n0 + r;
            return (n < 10000) ? (Wout + n * 512) : (const ushort_t*)nullptr;
        },
        [&](int mb, int l15, const f32x4* acc) {
            #pragma unroll
            for (int s = 0; s < 4; ++s) {
                int n = n0 + (s << 4) + l15;
                if (n >= 10000) continue;
                float bias = bf2f(bout[n]);
                #pragma unroll
                for (int r = 0; r < 4; ++r) {
                    int b = mb + r;
                    bool act = lengths[b] > t + 1;
                    float val = act ? (acc[s][r] + bias) : 0.f;
                    size_t off = (size_t)b * 310000 + t * 10000 + n;
                    if (f32o) ((float*)out_base)[off] = val;
                    else ((ushort_t*)out_base)[off] = act ? f2bf(val) : (ushort_t)0;
                }
            }
        });
}

extern "C" void kernel_launch(void* const* d_in, const int* in_sizes, int n_in,
                              void* d_out, int out_size, void* d_ws, size_t ws_size,
                              hipStream_t stream) {
    const void* features = d_in[0];
    const int* captions = (const int*)d_in[1];
    const int* lengths = (const int*)d_in[2];
    const void* W_emb = d_in[3];

    char* ws = (char*)d_ws;
    size_t o = 0;
    auto alloc = [&](size_t bytes) {
        size_t r = o;
        o += (bytes + 255) & ~(size_t)255;
        return r;
    };
    // canonical bf16 copies
    ushort_t* feat_c  = (ushort_t*)(ws + alloc(6422528ull * 2));
    ushort_t* Wenc_c  = (ushort_t*)(ws + alloc(262144ull * 2));
    ushort_t* benc_c  = (ushort_t*)(ws + alloc(512 * 2));
    ushort_t* W3c     = (ushort_t*)(ws + alloc(3072ull * 512 * 2));  // [Wdec;Wfb;Whh]
    ushort_t* bdec_c  = (ushort_t*)(ws + alloc(512 * 2));
    ushort_t* wfull_c = (ushort_t*)(ws + alloc(512 * 2));
    ushort_t* bfull_c = (ushort_t*)(ws + alloc(2));
    ushort_t* bfb_c   = (ushort_t*)(ws + alloc(512 * 2));
    ushort_t* Wih_c   = (ushort_t*)(ws + alloc(2097152ull * 2));
    ushort_t* bih_c   = (ushort_t*)(ws + alloc(2048 * 2));
    ushort_t* bhh_c   = (ushort_t*)(ws + alloc(2048 * 2));
    ushort_t* Wout_c  = (ushort_t*)(ws + alloc(5120000ull * 2));
    ushort_t* bout_c  = (ushort_t*)(ws + alloc(10000 * 2));
    ushort_t* Winh_c  = (ushort_t*)(ws + alloc(262144ull * 2));
    ushort_t* binh_c  = (ushort_t*)(ws + alloc(512 * 2));
    ushort_t* Winc_c  = (ushort_t*)(ws + alloc(262144ull * 2));
    ushort_t* binc_c  = (ushort_t*)(ws + alloc(512 * 2));
    ushort_t* emb_c   = (ushort_t*)(ws + alloc(1984ull * 512 * 2));
    // intermediates
    ushort_t* en_att  = (ushort_t*)(ws + alloc(12544ull * 512 * 2));
    float*    ec      = (float*)(ws + alloc(1984ull * 2048 * 4));
    ushort_t* H_all   = (ushort_t*)(ws + alloc(1984ull * 512 * 2));
    ushort_t* h_bf    = (ushort_t*)(ws + alloc(64 * 512 * 2));
    float*    cbuf    = (float*)(ws + alloc(64 * 512 * 4));
    float*    deK     = (float*)(ws + alloc(64 * 512 * 4));
    float*    fgate   = (float*)(ws + alloc(64 * 512 * 4));
    float*    hh      = (float*)(ws + alloc(64ull * 2048 * 4));
    ushort_t* z_bf    = (ushort_t*)(ws + alloc(64 * 512 * 2));
    ushort_t* mean_bf = (ushort_t*)(ws + alloc(64 * 512 * 2));
    float*    fullv   = (float*)(ws + alloc(64 * 196 * 4));
    float*    w2buf   = (float*)(ws + alloc(513 * 4));
    int*      flag    = (int*)(ws + alloc(256));
    int*      flags   = (int*)(ws + alloc(1024 * 4));

    detect_kernel<<<1, 64, 0, stream>>>((const unsigned*)features, flag, flags);

    CvtArgs ca;
    const void* srcs[NCVT] = {features, d_in[4], d_in[5], d_in[6], d_in[7], d_in[8],
                              d_in[9], d_in[10], d_in[11], d_in[12], d_in[13], d_in[14],
                              d_in[15], d_in[16], d_in[17], d_in[18], d_in[19], d_in[20],
                              d_in[21]};
    void* dsts[NCVT] = {feat_c, Wenc_c, benc_c, W3c /*Wdec*/, bdec_c, wfull_c, bfull_c,
                        W3c + 262144 /*Wfb*/, bfb_c, Wih_c, W3c + 524288 /*Whh*/,
                        bih_c, bhh_c, Wout_c, bout_c, Winh_c, binh_c, Winc_c, binc_c};
    int ns[NCVT] = {6422528, 262144, 512, 262144, 512, 512, 1, 262144, 512,
                    2097152, 1048576, 2048, 2048, 5120000, 10000, 262144, 512,
                    262144, 512};
    for (int i = 0; i < NCVT; ++i) {
        ca.src[i] = srcs[i];
        ca.dst[i] = dsts[i];
        ca.n[i] = ns[i];
    }
    convert_kernel<<<dim3(3136, NCVT), 256, 0, stream>>>(ca, flag);
    embrows_kernel<<<1984, 256, 0, stream>>>(W_emb, captions, flag, emb_c);
    prepw2_kernel<<<1, 512, 0, stream>>>(wfull_c, bfull_c, w2buf);

    mean_kernel<<<64, 256, 0, stream>>>(feat_c, mean_bf);
    init_kernel<<<16, 256, 0, stream>>>(mean_bf, Winh_c, binh_c, Winc_c, binc_c,
                                        h_bf, cbuf);
    enatt_kernel<<<dim3(8, 196), 256, 0, stream>>>(feat_c, Wenc_c, benc_c, en_att);
    ec_kernel<<<dim3(32, 31), 256, 0, stream>>>(emb_c, Wih_c, bih_c, bhh_c, ec);

    LoopArgs la;
    la.W3c = W3c; la.bdec = bdec_c; la.bfb = bfb_c;
    la.en_att = en_att; la.feat = feat_c; la.Wih = Wih_c;
    la.w2 = w2buf; la.ec = ec; la.lengths = lengths; la.flag = flag;
    la.h_bf = h_bf; la.z_bf = z_bf; la.H_all = H_all;
    la.cbuf = cbuf; la.deK = deK; la.fgate = fgate; la.hh = hh;
    la.fullv = fullv; la.out_base = d_out; la.flags = flags;
    loop_kernel<<<256, 512, 0, stream>>>(la);

    preds_kernel<<<dim3(31, 157), 256, 0, stream>>>(H_all, Wout_c, bout_c, lengths,
                                                    flag, d_out);
}